// Round 13
// baseline (42269.751 us; speedup 1.0000x reference)
//
#include <hip/hip_runtime.h>
#include <hip/hip_bf16.h>

// bigRSNN: T=8192 strictly-serial spiking RNN.
// Phase 1: 16 blocks x 576 threads (r12 protocol, NBLK sweep 32->16 to test
// the poller-pressure axis: device pollers 1000->480, flag fan-out 31->15,
// visibility-tail max over 15 not 31).
//   Waves 0..7 compute 64 rows (8/wave, 8 lanes/row, 128 V-cols/lane in 32
//   float4 VGPRs). Wave 8 = sync wave: lanes j=0..31 poll (producer j>>1,
//   half j&1) tagged u64s in the block's private 256-B mailbox sector
//   (relaxed agent atomic loads - the only proven-coherent path), write
//   payloads into the LDS ring, bump rdySync (relaxed, lgkm-fenced).
//   Publish: per-wave ballot -> 8-bit row byte -> LDS u64 bit-combiner +
//   count; last-arriving wave (count==8) broadcasts the 64 spike bits,
//   lanes 0..31 scatter two tagged u64s {(t+1)<<16|b16,(t+1)<<16|b16} to
//   each of the 15 remote consumers' sectors, lane0 re-arms, writes own
//   bits to LDS, bumps rdyOwn, then the raw u64 raster (off-path).
//   No barriers in the step loop; RING=4 (reuse safety via the cross-block
//   dependency chain; tags monotone).
// Phase 2: readout GEMM over the u64 raster + 10 IIR scans + head mean.

constexpr int T_STEPS = 8192;
constexpr int IN_DIM  = 192;
constexpr int H_DIM   = 1024;
constexpr int NBLK    = 16;
constexpr int RING    = 4;

// ---------------------------------------------------------------- clear ws
__global__ void k_clear(unsigned int* __restrict__ p, int n) {
    int i = blockIdx.x * blockDim.x + threadIdx.x;
    if (i < n) p[i] = 0u;
}

// ---------------------------------------------------------------- phase 1
__global__ __launch_bounds__(576, 1) void k_phase1(
    const float* __restrict__ x,        // [T][192]
    const float* __restrict__ W_in,     // [H][192]
    const float* __restrict__ V,        // [H][H]
    const float* __restrict__ b_rec,    // [H]
    const float* __restrict__ alpha_h_p,
    const float* __restrict__ beta_h_p,
    unsigned long long* __restrict__ mbox,  // [RING][16 cons][32 words] u64
    unsigned long long* __restrict__ raster) // [T][16] raw 64-bit spike words
{
    const int tid   = threadIdx.x;
    const int blk   = blockIdx.x;        // 0..15
    const int w     = tid >> 6;          // wave 0..8
    const int l     = tid & 63;
    const bool syncw = (w == 8);
    const int r_local = l >> 3;          // 0..7 (row within wave)
    const int cg      = l & 7;           // column group: cols cg*128..+127
    const int row   = (blk << 6) + (w << 3) + r_local; // compute waves only

    __shared__ __align__(16) unsigned int bits_lds[RING][2 * NBLK]; // 32-bit payloads
    __shared__ unsigned long long cbits[2];   // 64 spike bits, byte per wave
    __shared__ unsigned int       ccnt[2];    // arrival count
    __shared__ unsigned long long rdyPack;    // lo=rdySync, hi=rdyOwn

    for (int i = tid; i < RING * 2 * NBLK; i += 576)
        ((unsigned int*)bits_lds)[i] = 0u;
    if (tid == 0) {
        cbits[0] = 0ull; cbits[1] = 0ull;
        ccnt[0] = 0u; ccnt[1] = 0u; rdyPack = 0ull;
    }
    unsigned int* rp = (unsigned int*)&rdyPack;   // rp[0]=sync, rp[1]=own

    // ---- compute-wave register state ----
    float4 vfrag[32];
    float  wfrag[24];
    float  b_r = 0.f;
    if (!syncw) {
        const float4* vp = (const float4*)(V + (size_t)row * H_DIM + cg * 128);
        #pragma unroll
        for (int i = 0; i < 32; ++i) vfrag[i] = vp[i];
        const float4* wp = (const float4*)(W_in + row * IN_DIM + cg * 24);
        #pragma unroll
        for (int i = 0; i < 6; ++i) {
            float4 v4 = wp[i];
            wfrag[4 * i]     = v4.x; wfrag[4 * i + 1] = v4.y;
            wfrag[4 * i + 2] = v4.z; wfrag[4 * i + 3] = v4.w;
        }
        b_r = b_rec[row];
    }
    const float ah = alpha_h_p[0];
    const float bh = beta_h_p[0];

    __syncthreads();   // init visible to all waves (once, outside the loop)

    // burn-chain registers (asm sink prevents DCE)
    float u0 = 1.02f, u1 = 1.03f, u2 = 1.05f, u3 = 1.07f;
    const float bc = 1.0000001f, bd = 1e-30f;

    if (syncw) {
        // ---- sync wave: free-running mailbox -> LDS pump ----
        const int p_idx = l >> 1;          // producer 0..15 (lanes 0..31)
        const bool act = (l < 2 * NBLK) && (p_idx != blk);
        for (int t = 0; t < T_STEPS - 1; ++t) {
            const unsigned int want = (unsigned int)(t + 1);
            const unsigned long long* p =
                &mbox[(size_t)(((t & (RING - 1)) * NBLK + blk) * 2 * NBLK) + (l & 31)];
            unsigned long long vv = act
                ? __hip_atomic_load(p, __ATOMIC_RELAXED, __HIP_MEMORY_SCOPE_AGENT)
                : (((unsigned long long)want << 16) | ((unsigned long long)want << 48));
            bool ok = (((vv >> 16) & 0xffffull) == want) && ((vv >> 48) == want);
            while (__any(!ok)) {
                if (!ok)
                    vv = __hip_atomic_load(p, __ATOMIC_RELAXED,
                                           __HIP_MEMORY_SCOPE_AGENT);
                #pragma unroll
                for (int i = 0; i < 8; ++i) {   // burn under load latency
                    u0 = fmaf(u0, bc, bd); u1 = fmaf(u1, bc, bd);
                    u2 = fmaf(u2, bc, bd); u3 = fmaf(u3, bc, bd);
                }
                ok = (((vv >> 16) & 0xffffull) == want) && ((vv >> 48) == want);
            }
            if (act)
                bits_lds[t & (RING - 1)][l & 31] =
                    (unsigned int)(vv & 0xffffull)
                    | ((unsigned int)((vv >> 32) & 0xffffull) << 16);
            asm volatile("s_waitcnt lgkmcnt(0)" ::: "memory");
            __builtin_amdgcn_sched_barrier(0);
            if (l == 0)
                __hip_atomic_store(&rp[0], (unsigned int)(t + 1),
                                   __ATOMIC_RELAXED, __HIP_MEMORY_SCOPE_WORKGROUP);
        }
    } else {
        // ---- compute waves ----
        float syn = 0.f, mem = 0.f, prev = 0.f;

        for (int t = 0; t < T_STEPS; ++t) {
            // issue x[t-1] loads BEFORE the spin (latency hides under it)
            float4 xf[6];
            if (t > 0) {
                const float4* xp4 =
                    (const float4*)(x + (size_t)(t - 1) * IN_DIM + cg * 24);
                #pragma unroll
                for (int i = 0; i < 6; ++i) xf[i] = xp4[i];
            } else {
                #pragma unroll
                for (int i = 0; i < 6; ++i) xf[i] = make_float4(0.f, 0.f, 0.f, 0.f);
            }

            // acquire-spin: remote (rdySync>=t) and own (rdyOwn>=t)
            unsigned long long rv = __hip_atomic_load(&rdyPack, __ATOMIC_ACQUIRE,
                                        __HIP_MEMORY_SCOPE_WORKGROUP);
            while ((unsigned int)rv < (unsigned int)t ||
                   (unsigned int)(rv >> 32) < (unsigned int)t) {
                #pragma unroll
                for (int i = 0; i < 4; ++i) {
                    u0 = fmaf(u0, bc, bd); u1 = fmaf(u1, bc, bd);
                    u2 = fmaf(u2, bc, bd); u3 = fmaf(u3, bc, bd);
                }
                rv = __hip_atomic_load(&rdyPack, __ATOMIC_ACQUIRE,
                                       __HIP_MEMORY_SCOPE_WORKGROUP);
            }

            const int slot = (t + RING - 1) & (RING - 1);   // (t-1) & 3
            const uint4 bb = *reinterpret_cast<const uint4*>(&bits_lds[slot][4 * cg]);
            const unsigned int b0 = bb.x, b1 = bb.y, b2 = bb.z, b3 = bb.w;

            // V @ S_{t-1} over my 128 columns (four parallel FMA chains)
            float a0 = 0.f, a1 = 0.f, a2 = 0.f, a3 = 0.f;
            #pragma unroll
            for (int i = 0; i < 8; ++i) {
                a0 = fmaf((float)((b0 >> (4 * i + 0)) & 1u), vfrag[i].x, a0);
                a0 = fmaf((float)((b0 >> (4 * i + 1)) & 1u), vfrag[i].y, a0);
                a0 = fmaf((float)((b0 >> (4 * i + 2)) & 1u), vfrag[i].z, a0);
                a0 = fmaf((float)((b0 >> (4 * i + 3)) & 1u), vfrag[i].w, a0);
                a1 = fmaf((float)((b1 >> (4 * i + 0)) & 1u), vfrag[8 + i].x, a1);
                a1 = fmaf((float)((b1 >> (4 * i + 1)) & 1u), vfrag[8 + i].y, a1);
                a1 = fmaf((float)((b1 >> (4 * i + 2)) & 1u), vfrag[8 + i].z, a1);
                a1 = fmaf((float)((b1 >> (4 * i + 3)) & 1u), vfrag[8 + i].w, a1);
                a2 = fmaf((float)((b2 >> (4 * i + 0)) & 1u), vfrag[16 + i].x, a2);
                a2 = fmaf((float)((b2 >> (4 * i + 1)) & 1u), vfrag[16 + i].y, a2);
                a2 = fmaf((float)((b2 >> (4 * i + 2)) & 1u), vfrag[16 + i].z, a2);
                a2 = fmaf((float)((b2 >> (4 * i + 3)) & 1u), vfrag[16 + i].w, a2);
                a3 = fmaf((float)((b3 >> (4 * i + 0)) & 1u), vfrag[24 + i].x, a3);
                a3 = fmaf((float)((b3 >> (4 * i + 1)) & 1u), vfrag[24 + i].y, a3);
                a3 = fmaf((float)((b3 >> (4 * i + 2)) & 1u), vfrag[24 + i].z, a3);
                a3 = fmaf((float)((b3 >> (4 * i + 3)) & 1u), vfrag[24 + i].w, a3);
            }
            // + W_in @ x[t-1] over my 24 k's (spread across the 4 chains)
            #pragma unroll
            for (int i = 0; i < 6; ++i) {
                a0 = fmaf(wfrag[4 * i],     xf[i].x, a0);
                a1 = fmaf(wfrag[4 * i + 1], xf[i].y, a1);
                a2 = fmaf(wfrag[4 * i + 2], xf[i].z, a2);
                a3 = fmaf(wfrag[4 * i + 3], xf[i].w, a3);
            }
            float acc = (a0 + a1) + (a2 + a3);

            // reduce across the row's 8 lanes
            #pragma unroll
            for (int m = 1; m < 8; m <<= 1) acc += __shfl_xor(acc, m, 64);

            // state update (identical across the row's 8 lanes)
            float cur = acc + b_r;
            syn = fmaf(ah, syn, cur);
            mem = fmaf(bh, mem, syn) * (1.0f - prev);   // zero-reset, prev spike
            float spk = (mem > 1.0f) ? 1.0f : 0.0f;
            prev = spk;

            // ---- combine: ballot -> row byte -> LDS bit-OR (add) + count ----
            const int wsl = t & 1;
            unsigned long long bal = __ballot(spk > 0.5f);
            unsigned int isLast = 0u;
            unsigned long long bits64 = 0ull;
            if (l == 0) {
                unsigned int byte = 0u;
                #pragma unroll
                for (int r = 0; r < 8; ++r)
                    byte |= ((unsigned int)(bal >> (8 * r)) & 1u) << r;
                __hip_atomic_fetch_add(&cbits[wsl],
                        (unsigned long long)byte << (8 * w),
                        __ATOMIC_RELAXED, __HIP_MEMORY_SCOPE_WORKGROUP);
                asm volatile("s_waitcnt lgkmcnt(0)" ::: "memory");
                unsigned int oldc = __hip_atomic_fetch_add(&ccnt[wsl], 1u,
                        __ATOMIC_RELAXED, __HIP_MEMORY_SCOPE_WORKGROUP);
                if (oldc == 7u) {
                    isLast = 1u;
                    bits64 = __hip_atomic_load(&cbits[wsl], __ATOMIC_RELAXED,
                                               __HIP_MEMORY_SCOPE_WORKGROUP);
                }
            }
            isLast = __shfl(isLast, 0, 64);
            if (isLast) {
                bits64 = __shfl(bits64, 0, 64);
                const unsigned int want = (unsigned int)(t + 1);
                // lanes 0..31: (consumer l>>1, half l&1) tagged u64 push
                if (l < 2 * NBLK) {
                    const int c = l >> 1, h = l & 1;
                    if (c != blk) {
                        unsigned int chunk = (unsigned int)(bits64 >> (32 * h));
                        unsigned int w0t = (want << 16) | (chunk & 0xffffu);
                        unsigned int w1t = (want << 16) | (chunk >> 16);
                        unsigned long long pack =
                            (unsigned long long)w0t | ((unsigned long long)w1t << 32);
                        __hip_atomic_store(
                            &mbox[(size_t)(((t & (RING - 1)) * NBLK + c) * 2 * NBLK)
                                  + (blk * 2 + h)],
                            pack, __ATOMIC_RELAXED, __HIP_MEMORY_SCOPE_AGENT);
                    }
                }
                if (l == 0) {
                    bits_lds[t & (RING - 1)][blk * 2]     = (unsigned int)bits64;
                    bits_lds[t & (RING - 1)][blk * 2 + 1] = (unsigned int)(bits64 >> 32);
                    __hip_atomic_store(&cbits[wsl], 0ull, __ATOMIC_RELAXED,
                                       __HIP_MEMORY_SCOPE_WORKGROUP);
                    __hip_atomic_store(&ccnt[wsl], 0u, __ATOMIC_RELAXED,
                                       __HIP_MEMORY_SCOPE_WORKGROUP);
                    asm volatile("s_waitcnt lgkmcnt(0)" ::: "memory");
                    __builtin_amdgcn_sched_barrier(0);
                    __hip_atomic_store(&rp[1], (unsigned int)(t + 1),
                                       __ATOMIC_RELAXED,
                                       __HIP_MEMORY_SCOPE_WORKGROUP);
                    raster[(size_t)t * NBLK + blk] = bits64;   // off-path
                }
            }
        }
    }
    asm volatile("" :: "v"(u0), "v"(u1), "v"(u2), "v"(u3));
}

// ---------------------------------------------------------------- phase 2A
// R[t][rr] = W_out[rr] . S_{t-1}  (rr = h*2+o, 10 rows). W_out staged in LDS
// with pad (stride 1033) to break row-bank conflicts.
__global__ __launch_bounds__(256, 1) void k_readout_mm(
    const unsigned long long* __restrict__ raster,  // [T][16] raw spike words
    const float* __restrict__ W_out,   // [10][1024]
    float* __restrict__ R)             // [T][10]
{
    __shared__ float wlds[10 * 1033];
    for (int i = threadIdx.x; i < 10 * 1024; i += 256) {
        int r = i >> 10, c = i & 1023;
        wlds[r * 1033 + c] = W_out[i];
    }
    __syncthreads();

    int tid = threadIdx.x;
    if (tid >= 250) return;
    int tl = tid / 10, rowr = tid - tl * 10;
    int t = blockIdx.x * 25 + tl;
    if (t >= T_STEPS) return;

    float acc = 0.f;
    if (t > 0) {
        const unsigned long long* wp = raster + (size_t)(t - 1) * NBLK;
        const float* wr = &wlds[rowr * 1033];
        for (int ww = 0; ww < NBLK; ++ww) {
            unsigned long long bits = wp[ww];
            const float* wb = wr + ww * 64;
            #pragma unroll
            for (int j = 0; j < 64; ++j)
                acc = fmaf((float)((bits >> j) & 1ull), wb[j], acc);
        }
    }
    R[t * 10 + rowr] = acc;
}

// ---------------------------------------------------------------- phase 2B
__global__ void k_scan(const float* __restrict__ R,
                       const float* __restrict__ alpha_r,
                       const float* __restrict__ beta_r,
                       float* __restrict__ memr_all)   // [T][10]
{
    int lane = threadIdx.x;
    bool act = lane < 10;
    float a = act ? alpha_r[lane >> 1] : 0.f;
    float b = act ? beta_r[lane >> 1] : 0.f;
    float syn = 0.f, mem = 0.f;
    constexpr int PF = 8;
    float buf[PF];
    #pragma unroll
    for (int i = 0; i < PF; ++i) buf[i] = act ? R[i * 10 + lane] : 0.f;

    for (int tb = 0; tb < T_STEPS; tb += PF) {
        #pragma unroll
        for (int i = 0; i < PF; ++i) {
            int t = tb + i;
            syn = fmaf(a, syn, buf[i]);
            mem = fmaf(b, mem, syn);
            if (act) memr_all[t * 10 + lane] = mem;
            int tn = t + PF;
            buf[i] = (act && tn < T_STEPS) ? R[tn * 10 + lane] : 0.f;
        }
    }
}

// ---------------------------------------------------------------- phase 2C
__global__ void k_mean(const float* __restrict__ memr_all, float* __restrict__ out) {
    int g = blockIdx.x * blockDim.x + threadIdx.x;
    if (g >= T_STEPS * 2) return;
    int t = g >> 1, o = g & 1;
    const float* m = memr_all + t * 10 + o;
    out[g] = 0.2f * (m[0] + m[2] + m[4] + m[6] + m[8]);
}

// ---------------------------------------------------------------- launch
extern "C" void kernel_launch(void* const* d_in, const int* in_sizes, int n_in,
                              void* d_out, int out_size, void* d_ws, size_t ws_size,
                              hipStream_t stream) {
    (void)in_sizes; (void)n_in; (void)out_size; (void)ws_size;
    const float* x       = (const float*)d_in[0];
    const float* W_in    = (const float*)d_in[1];
    const float* V       = (const float*)d_in[2];
    const float* b_rec   = (const float*)d_in[3];
    const float* W_out   = (const float*)d_in[4];
    const float* alpha_h = (const float*)d_in[5];
    const float* beta_h  = (const float*)d_in[6];
    const float* alpha_r = (const float*)d_in[7];
    const float* beta_r  = (const float*)d_in[8];
    float* out = (float*)d_out;

    char* wsb = (char*)d_ws;
    // mbox: RING * 16 consumers * 32 words * 8B = 16 KB
    unsigned long long* mbox = (unsigned long long*)wsb;
    unsigned long long* raster =
        (unsigned long long*)(wsb + RING * NBLK * 2 * NBLK * 8);      // 1 MB
    float* Rbuf    = (float*)(wsb + RING * NBLK * 2 * NBLK * 8
                              + (size_t)T_STEPS * NBLK * 8);          // 320 KB
    float* memr_all = Rbuf + (size_t)T_STEPS * 10;                    // 320 KB

    int nclr = RING * NBLK * 2 * NBLK * 2;   // mailbox region in u32s
    k_clear<<<(nclr + 255) / 256, 256, 0, stream>>>((unsigned int*)mbox, nclr);
    k_phase1<<<NBLK, 576, 0, stream>>>(x, W_in, V, b_rec, alpha_h, beta_h,
                                       mbox, raster);
    k_readout_mm<<<(T_STEPS + 24) / 25, 256, 0, stream>>>(raster, W_out, Rbuf);
    k_scan<<<1, 64, 0, stream>>>(Rbuf, alpha_r, beta_r, memr_all);
    k_mean<<<(T_STEPS * 2 + 255) / 256, 256, 0, stream>>>(memr_all, out);
}

// Round 14
// 20143.524 us; speedup vs baseline: 2.0984x; 2.0984x over previous
//
#include <hip/hip_runtime.h>
#include <hip/hip_bf16.h>

// bigRSNN: T=8192 strictly-serial spiking RNN.
// Phase 1: 32 blocks x 576 threads, barrier-free step loop (r12 structure =
// best measured 17.2ms) + ONE change: the sync wave polls its mailbox sector
// with a DEPTH-4 compiler-built pipelined rotation (4 relaxed agent atomic
// loads in flight into named regs; SIInsertWaitcnts emits per-register
// vmcnt(N) waits). Sampling period drops ~900cy -> ~225cy, attacking the
// poll-quantization term (~0.3-0.45us of the 2.1us step). r11 tested this
// WITH release bumps whose vmcnt(0) drained the 3 dead in-flight polls every
// step (poisoned test); bumps here stay RELAXED after lgkmcnt(0)-only
// fences (r12's fix). Geometry stays r12's 64 cols/lane (72 VGPR — r13
// proved 128 cols/lane spills V out of registers, VGPR_Count=84 < needed).
//   Waves 0..7 compute 32 rows (4/wave, 16 lanes/row, 64 V-cols/lane in
//   VGPRs); wave 8 = sync wave -> LDS ring handoff. Publish: LDS u64
//   combiner; last-arriving wave scatter-stores the tagged 8-B flag
//   {(t+1)<<16|lo16,(t+1)<<16|hi16} to the 31 remote sectors (relaxed agent
//   atomic stores - the only proven-coherent path), bumps rdyOwn; raster
//   write after the bump (off-path). RING=4.
// Phase 2: readout GEMM over the tagged raster + 10 IIR scans + head mean.

constexpr int T_STEPS = 8192;
constexpr int IN_DIM  = 192;
constexpr int H_DIM   = 1024;
constexpr int NBLK    = 32;
constexpr int RING    = 4;

#define LOADP() __hip_atomic_load(pa, __ATOMIC_RELAXED, __HIP_MEMORY_SCOPE_AGENT)
#define GOOD(v) ((((v) >> 16) & 0xffffull) == want && ((v) >> 48) == want)
#define POLL_STEP(ri) \
    if (!ok && GOOD(ri)) { word = ri; ok = true; } \
    if (__all(ok)) break; \
    ri = LOADP();

// ---------------------------------------------------------------- clear ws
__global__ void k_clear(unsigned int* __restrict__ p, int n) {
    int i = blockIdx.x * blockDim.x + threadIdx.x;
    if (i < n) p[i] = 0u;
}

// ---------------------------------------------------------------- phase 1
__global__ __launch_bounds__(576, 1) void k_phase1(
    const float* __restrict__ x,        // [T][192]
    const float* __restrict__ W_in,     // [H][192]
    const float* __restrict__ V,        // [H][H]
    const float* __restrict__ b_rec,    // [H]
    const float* __restrict__ alpha_h_p,
    const float* __restrict__ beta_h_p,
    unsigned long long* __restrict__ mbox,  // [RING][32 cons][32 prod] u64
    uint2* __restrict__ raster)         // [T][32] tagged words
{
    const int tid   = threadIdx.x;
    const int blk   = blockIdx.x;        // 0..31
    const int w     = tid >> 6;          // wave 0..8
    const int l     = tid & 63;
    const bool syncw = (w == 8);
    const int r_local = l >> 4;          // 0..3 (row within wave)
    const int cg      = l & 15;          // column group: cols cg*64..+63
    const int row   = (blk << 5) + (w << 2) + r_local; // compute waves only

    __shared__ unsigned int       bits_lds[RING][NBLK]; // slot = step&3
    __shared__ unsigned long long combine[2];           // low32 bits|count<<32
    __shared__ unsigned long long rdyPack;              // lo=rdySync, hi=rdyOwn

    for (int i = tid; i < RING * NBLK; i += 576)
        ((unsigned int*)bits_lds)[i] = 0u;
    if (tid == 0) { combine[0] = 0ull; combine[1] = 0ull; rdyPack = 0ull; }

    unsigned int* rp = (unsigned int*)&rdyPack;   // rp[0]=sync, rp[1]=own

    // ---- compute-wave register state ----
    float4 vfrag[16];
    float  wfrag[12];
    float  b_r = 0.f;
    if (!syncw) {
        const float4* vp = (const float4*)(V + (size_t)row * H_DIM + cg * 64);
        #pragma unroll
        for (int i = 0; i < 16; ++i) vfrag[i] = vp[i];
        const float* wp = W_in + row * IN_DIM + cg * 12;
        #pragma unroll
        for (int i = 0; i < 12; ++i) wfrag[i] = wp[i];
        b_r = b_rec[row];
    }
    const float ah = alpha_h_p[0];
    const float bh = beta_h_p[0];

    __syncthreads();   // init visible to all waves (once, outside the loop)

    // burn-chain registers (escape via asm sink so they can't be DCE'd)
    float u0 = 1.02f, u1 = 1.03f, u2 = 1.05f, u3 = 1.07f;
    const float bc = 1.0000001f, bd = 1e-30f;

    if (syncw) {
        // ---- sync wave: depth-4 pipelined mailbox poll -> LDS pump ----
        const bool act = (l < NBLK) && (l != blk);
        for (int t = 0; t < T_STEPS - 1; ++t) {
            const unsigned long long want = (unsigned long long)(t + 1);
            const unsigned long long* pa =
                &mbox[(size_t)(((t & (RING - 1)) * NBLK + blk) * NBLK) + (l & 31)];
            unsigned long long word = (want << 16) | (want << 48);
            bool ok = !act;
            unsigned long long r0 = LOADP(), r1 = LOADP(),
                               r2 = LOADP(), r3 = LOADP();
            for (;;) {
                POLL_STEP(r0)
                POLL_STEP(r1)
                POLL_STEP(r2)
                POLL_STEP(r3)
                u0 = fmaf(u0, bc, bd); u1 = fmaf(u1, bc, bd);   // burn
            }
            if (act)
                bits_lds[t & (RING - 1)][l] =
                    (unsigned int)(word & 0xffffull)
                    | ((unsigned int)((word >> 32) & 0xffffull) << 16);
            // LDS-only fence, then relaxed bump (no vmcnt drain!)
            asm volatile("s_waitcnt lgkmcnt(0)" ::: "memory");
            __builtin_amdgcn_sched_barrier(0);
            if (l == 0)
                __hip_atomic_store(&rp[0], (unsigned int)(t + 1),
                                   __ATOMIC_RELAXED, __HIP_MEMORY_SCOPE_WORKGROUP);
        }
    } else {
        // ------------- compute waves -------------
        const float* xptr = x + cg * 12;
        float xr[12];
        #pragma unroll
        for (int i = 0; i < 12; ++i) xr[i] = 0.0f;   // x[-1] = 0
        float syn = 0.f, mem = 0.f, prev = 0.f;

        for (int t = 0; t < T_STEPS; ++t) {
            // issue x[t] prefetch (consumed next step); overlaps the spin
            const float4* xp4 = (const float4*)xptr;
            float4 f0 = xp4[0], f1 = xp4[1], f2 = xp4[2];

            // acquire-spin: remote bits (rdySync>=t) and own bits (rdyOwn>=t)
            unsigned long long rv = __hip_atomic_load(&rdyPack, __ATOMIC_ACQUIRE,
                                        __HIP_MEMORY_SCOPE_WORKGROUP);
            while ((unsigned int)rv < (unsigned int)t ||
                   (unsigned int)(rv >> 32) < (unsigned int)t) {
                #pragma unroll
                for (int i = 0; i < 4; ++i) {   // burn under LDS latency
                    u0 = fmaf(u0, bc, bd); u1 = fmaf(u1, bc, bd);
                    u2 = fmaf(u2, bc, bd); u3 = fmaf(u3, bc, bd);
                }
                rv = __hip_atomic_load(&rdyPack, __ATOMIC_ACQUIRE,
                                       __HIP_MEMORY_SCOPE_WORKGROUP);
            }

            const int slot = (t + RING - 1) & (RING - 1);   // (t-1) & 3
            unsigned int b0 = bits_lds[slot][2 * cg];       // cols cg*64..+31
            unsigned int b1 = bits_lds[slot][2 * cg + 1];   // cols +32..+63

            // V @ S_{t-1} over my 64 columns (two parallel FMA chains)
            float a0 = 0.f, a1 = 0.f;
            #pragma unroll
            for (int i = 0; i < 8; ++i) {
                a0 = fmaf((float)((b0 >> (4 * i + 0)) & 1u), vfrag[i].x, a0);
                a0 = fmaf((float)((b0 >> (4 * i + 1)) & 1u), vfrag[i].y, a0);
                a0 = fmaf((float)((b0 >> (4 * i + 2)) & 1u), vfrag[i].z, a0);
                a0 = fmaf((float)((b0 >> (4 * i + 3)) & 1u), vfrag[i].w, a0);
                a1 = fmaf((float)((b1 >> (4 * i + 0)) & 1u), vfrag[8 + i].x, a1);
                a1 = fmaf((float)((b1 >> (4 * i + 1)) & 1u), vfrag[8 + i].y, a1);
                a1 = fmaf((float)((b1 >> (4 * i + 2)) & 1u), vfrag[8 + i].z, a1);
                a1 = fmaf((float)((b1 >> (4 * i + 3)) & 1u), vfrag[8 + i].w, a1);
            }
            // + W_in @ x[t-1] over my 12 k's
            #pragma unroll
            for (int i = 0; i < 12; ++i) a0 = fmaf(wfrag[i], xr[i], a0);
            float acc = a0 + a1;

            // reduce across the row's 16 lanes
            #pragma unroll
            for (int m = 1; m < 16; m <<= 1) acc += __shfl_xor(acc, m, 64);

            // state update (identical across the row's 16 lanes)
            float cur = acc + b_r;
            syn = fmaf(ah, syn, cur);
            mem = fmaf(bh, mem, syn) * (1.0f - prev);   // zero-reset, prev spike
            float spk = (mem > 1.0f) ? 1.0f : 0.0f;
            prev = spk;

            // combine: ballot -> lane0 packs 4-bit nibble -> LDS u64 add
            unsigned long long bal = __ballot(spk > 0.5f);
            unsigned int isLast = 0u, bitsAll = 0u;
            if (l == 0) {
                unsigned int nib = (unsigned int)(bal & 1ull)
                                 | ((unsigned int)((bal >> 16) & 1ull) << 1)
                                 | ((unsigned int)((bal >> 32) & 1ull) << 2)
                                 | ((unsigned int)((bal >> 48) & 1ull) << 3);
                unsigned long long add =
                    (1ull << 32) | ((unsigned long long)nib << (4 * w));
                unsigned long long old = __hip_atomic_fetch_add(&combine[t & 1],
                        add, __ATOMIC_RELAXED, __HIP_MEMORY_SCOPE_WORKGROUP);
                unsigned long long nv = old + add;
                if ((nv >> 32) == 8ull) { isLast = 1u; bitsAll = (unsigned int)nv; }
            }
            isLast = __shfl(isLast, 0, 64);
            if (isLast) {
                unsigned int bits = __shfl(bitsAll, 0, 64);
                unsigned int want = (unsigned int)(t + 1);
                unsigned int w0t = (want << 16) | (bits & 0xffffu);
                unsigned int w1t = (want << 16) | (bits >> 16);
                unsigned long long pack =
                    (unsigned long long)w0t | ((unsigned long long)w1t << 32);
                // fire-and-forget: tagged flags are self-validating, no fence
                if (l < NBLK && l != blk) {
                    __hip_atomic_store(
                        &mbox[(size_t)(((t & (RING - 1)) * NBLK + l) * NBLK) + blk],
                        pack, __ATOMIC_RELAXED, __HIP_MEMORY_SCOPE_AGENT);
                }
                if (l == 0) {
                    bits_lds[t & (RING - 1)][blk] = bits;   // own bits
                    combine[t & 1] = 0ull;                  // re-arm for t+2
                    // LDS-only fence, then relaxed bump (no vmcnt drain)
                    asm volatile("s_waitcnt lgkmcnt(0)" ::: "memory");
                    __builtin_amdgcn_sched_barrier(0);
                    __hip_atomic_store(&rp[1], (unsigned int)(t + 1),
                                       __ATOMIC_RELAXED,
                                       __HIP_MEMORY_SCOPE_WORKGROUP);
                    // raster write AFTER the bump: off the critical path
                    raster[(size_t)t * NBLK + blk] = make_uint2(w0t, w1t);
                }
            }

            #pragma unroll
            for (int i = 0; i < 4; ++i) {
                xr[i]     = (&f0.x)[i];
                xr[4 + i] = (&f1.x)[i];
                xr[8 + i] = (&f2.x)[i];
            }
            xptr += IN_DIM;
        }
    }
    // keep burn chains alive (prevents DCE; negligible cost)
    asm volatile("" :: "v"(u0), "v"(u1), "v"(u2), "v"(u3));
}

// ---------------------------------------------------------------- phase 2A
// R[t][rr] = W_out[rr] . S_{t-1}  (rr = h*2+o, 10 rows). W_out staged in LDS
// with pad (stride 1033) to break row-bank conflicts.
__global__ __launch_bounds__(256, 1) void k_readout_mm(
    const uint2* __restrict__ raster,  // [T][32] tagged words
    const float* __restrict__ W_out,   // [10][1024]
    float* __restrict__ R)             // [T][10]
{
    __shared__ float wlds[10 * 1033];
    for (int i = threadIdx.x; i < 10 * 1024; i += 256) {
        int r = i >> 10, c = i & 1023;
        wlds[r * 1033 + c] = W_out[i];
    }
    __syncthreads();

    int tid = threadIdx.x;
    if (tid >= 250) return;
    int tl = tid / 10, rowr = tid - tl * 10;
    int t = blockIdx.x * 25 + tl;
    if (t >= T_STEPS) return;

    float acc = 0.f;
    if (t > 0) {
        const uint2* wp = raster + (size_t)(t - 1) * NBLK;
        const float* wr = &wlds[rowr * 1033];
        for (int ww = 0; ww < NBLK; ++ww) {
            uint2 v = wp[ww];
            unsigned int bits = (v.x & 0xffffu) | ((v.y & 0xffffu) << 16);
            const float* wb = wr + ww * 32;
            #pragma unroll
            for (int j = 0; j < 32; ++j)
                acc = fmaf((float)((bits >> j) & 1u), wb[j], acc);
        }
    }
    R[t * 10 + rowr] = acc;
}

// ---------------------------------------------------------------- phase 2B
__global__ void k_scan(const float* __restrict__ R,
                       const float* __restrict__ alpha_r,
                       const float* __restrict__ beta_r,
                       float* __restrict__ memr_all)   // [T][10]
{
    int lane = threadIdx.x;
    bool act = lane < 10;
    float a = act ? alpha_r[lane >> 1] : 0.f;
    float b = act ? beta_r[lane >> 1] : 0.f;
    float syn = 0.f, mem = 0.f;
    constexpr int PF = 8;
    float buf[PF];
    #pragma unroll
    for (int i = 0; i < PF; ++i) buf[i] = act ? R[i * 10 + lane] : 0.f;

    for (int tb = 0; tb < T_STEPS; tb += PF) {
        #pragma unroll
        for (int i = 0; i < PF; ++i) {
            int t = tb + i;
            syn = fmaf(a, syn, buf[i]);
            mem = fmaf(b, mem, syn);
            if (act) memr_all[t * 10 + lane] = mem;
            int tn = t + PF;
            buf[i] = (act && tn < T_STEPS) ? R[tn * 10 + lane] : 0.f;
        }
    }
}

// ---------------------------------------------------------------- phase 2C
__global__ void k_mean(const float* __restrict__ memr_all, float* __restrict__ out) {
    int g = blockIdx.x * blockDim.x + threadIdx.x;
    if (g >= T_STEPS * 2) return;
    int t = g >> 1, o = g & 1;
    const float* m = memr_all + t * 10 + o;
    out[g] = 0.2f * (m[0] + m[2] + m[4] + m[6] + m[8]);
}

// ---------------------------------------------------------------- launch
extern "C" void kernel_launch(void* const* d_in, const int* in_sizes, int n_in,
                              void* d_out, int out_size, void* d_ws, size_t ws_size,
                              hipStream_t stream) {
    (void)in_sizes; (void)n_in; (void)out_size; (void)ws_size;
    const float* x       = (const float*)d_in[0];
    const float* W_in    = (const float*)d_in[1];
    const float* V       = (const float*)d_in[2];
    const float* b_rec   = (const float*)d_in[3];
    const float* W_out   = (const float*)d_in[4];
    const float* alpha_h = (const float*)d_in[5];
    const float* beta_h  = (const float*)d_in[6];
    const float* alpha_r = (const float*)d_in[7];
    const float* beta_r  = (const float*)d_in[8];
    float* out = (float*)d_out;

    char* wsb = (char*)d_ws;
    unsigned long long* mbox = (unsigned long long*)wsb;   // 4*32*32*8 = 32 KB
    uint2* raster  = (uint2*)(wsb + RING * NBLK * NBLK * 8);          // 2 MB
    float* Rbuf    = (float*)(wsb + RING * NBLK * NBLK * 8
                              + (size_t)T_STEPS * NBLK * 8);          // 320 KB
    float* memr_all = Rbuf + (size_t)T_STEPS * 10;                    // 320 KB

    int nclr = RING * NBLK * NBLK * 2;   // mailbox region in u32s
    k_clear<<<(nclr + 255) / 256, 256, 0, stream>>>((unsigned int*)mbox, nclr);
    k_phase1<<<NBLK, 576, 0, stream>>>(x, W_in, V, b_rec, alpha_h, beta_h,
                                       mbox, raster);
    k_readout_mm<<<(T_STEPS + 24) / 25, 256, 0, stream>>>(raster, W_out, Rbuf);
    k_scan<<<1, 64, 0, stream>>>(Rbuf, alpha_r, beta_r, memr_all);
    k_mean<<<(T_STEPS * 2 + 255) / 256, 256, 0, stream>>>(memr_all, out);
}

// Round 15
// 17647.849 us; speedup vs baseline: 2.3952x; 1.1414x over previous
//
#include <hip/hip_runtime.h>
#include <hip/hip_bf16.h>

// bigRSNN: T=8192 strictly-serial spiking RNN.  == FINAL (r12 config) ==
// Best measured: 17.6 ms total, ~2.1 us/step. Latency-bound: 8192 serial
// cross-workgroup exchange rounds through the LLC (agent-scope atomics are
// the only coherent path on gfx950 — per-XCD L2 serves stale lines, r7).
// Swept and rejected: pull/padded/push/hedged-sc0/pipelined polls (depth
// 4/8 regress: poll concurrency delays store commit), 0/1/2 barriers,
// release vs relaxed fences, NBLK 64/16, DVFS burn blocks, single-XCD.
//
// Phase 1: 32 blocks x 576 threads, barrier-free step loop.
//   Waves 0..7 compute 32 rows (4/wave, 16 lanes/row, 64 V-cols/lane in
//   VGPRs; 72 VGPR total - register-resident V). Wave 8 = sync wave:
//   serial-polls its own push-mailbox sector (relaxed agent atomic loads),
//   writes remote bits into the LDS ring, bumps rdySync (relaxed, after an
//   lgkmcnt(0)-only fence - no vmcnt drain). Last-arriving compute wave
//   (LDS u64 combiner) scatter-stores the tagged 8-B flag
//   {(t+1)<<16|lo16,(t+1)<<16|hi16} to the 31 remote sectors, writes own
//   bits, bumps rdyOwn, then the raster (off-path). RING=4; tags monotone.
// Phase 2: readout GEMM over the tagged raster + 10 IIR scans + head mean.

constexpr int T_STEPS = 8192;
constexpr int IN_DIM  = 192;
constexpr int H_DIM   = 1024;
constexpr int NBLK    = 32;
constexpr int RING    = 4;

// ---------------------------------------------------------------- clear ws
__global__ void k_clear(unsigned int* __restrict__ p, int n) {
    int i = blockIdx.x * blockDim.x + threadIdx.x;
    if (i < n) p[i] = 0u;
}

// ---------------------------------------------------------------- phase 1
__global__ __launch_bounds__(576, 1) void k_phase1(
    const float* __restrict__ x,        // [T][192]
    const float* __restrict__ W_in,     // [H][192]
    const float* __restrict__ V,        // [H][H]
    const float* __restrict__ b_rec,    // [H]
    const float* __restrict__ alpha_h_p,
    const float* __restrict__ beta_h_p,
    unsigned long long* __restrict__ mbox,  // [RING][32 cons][32 prod] u64
    uint2* __restrict__ raster)         // [T][32] tagged words
{
    const int tid   = threadIdx.x;
    const int blk   = blockIdx.x;        // 0..31
    const int w     = tid >> 6;          // wave 0..8
    const int l     = tid & 63;
    const bool syncw = (w == 8);
    const int r_local = l >> 4;          // 0..3 (row within wave)
    const int cg      = l & 15;          // column group: cols cg*64..+63
    const int row   = (blk << 5) + (w << 2) + r_local; // compute waves only

    __shared__ unsigned int       bits_lds[RING][NBLK]; // slot = step&3
    __shared__ unsigned long long combine[2];           // low32 bits|count<<32
    __shared__ unsigned long long rdyPack;              // lo=rdySync, hi=rdyOwn

    for (int i = tid; i < RING * NBLK; i += 576)
        ((unsigned int*)bits_lds)[i] = 0u;
    if (tid == 0) { combine[0] = 0ull; combine[1] = 0ull; rdyPack = 0ull; }

    unsigned int* rp = (unsigned int*)&rdyPack;   // rp[0]=sync, rp[1]=own

    // ---- compute-wave register state ----
    float4 vfrag[16];
    float  wfrag[12];
    float  b_r = 0.f;
    if (!syncw) {
        const float4* vp = (const float4*)(V + (size_t)row * H_DIM + cg * 64);
        #pragma unroll
        for (int i = 0; i < 16; ++i) vfrag[i] = vp[i];
        const float* wp = W_in + row * IN_DIM + cg * 12;
        #pragma unroll
        for (int i = 0; i < 12; ++i) wfrag[i] = wp[i];
        b_r = b_rec[row];
    }
    const float ah = alpha_h_p[0];
    const float bh = beta_h_p[0];

    __syncthreads();   // init visible to all waves (once, outside the loop)

    // burn-chain registers (escape via asm sink so they can't be DCE'd)
    float u0 = 1.02f, u1 = 1.03f, u2 = 1.05f, u3 = 1.07f;
    const float bc = 1.0000001f, bd = 1e-30f;

    if (syncw) {
        // ------------- sync wave: free-running mailbox -> LDS pump -------------
        const bool act = (l < NBLK) && (l != blk);
        for (int t = 0; t < T_STEPS - 1; ++t) {
            const unsigned int want = (unsigned int)(t + 1);
            const unsigned long long* p =
                &mbox[(size_t)(((t & (RING - 1)) * NBLK + blk) * NBLK) + (l & 31)];
            unsigned long long vv = act
                ? __hip_atomic_load(p, __ATOMIC_RELAXED, __HIP_MEMORY_SCOPE_AGENT)
                : (((unsigned long long)want << 16) | ((unsigned long long)want << 48));
            bool ok = (((vv >> 16) & 0xffffull) == want) && ((vv >> 48) == want);
            while (__any(!ok)) {
                if (!ok)
                    vv = __hip_atomic_load(p, __ATOMIC_RELAXED,
                                           __HIP_MEMORY_SCOPE_AGENT);
                #pragma unroll
                for (int i = 0; i < 8; ++i) {   // burn under load latency
                    u0 = fmaf(u0, bc, bd); u1 = fmaf(u1, bc, bd);
                    u2 = fmaf(u2, bc, bd); u3 = fmaf(u3, bc, bd);
                }
                ok = (((vv >> 16) & 0xffffull) == want) && ((vv >> 48) == want);
            }
            if (act)
                bits_lds[t & (RING - 1)][l] =
                    (unsigned int)(vv & 0xffffull)
                    | ((unsigned int)((vv >> 32) & 0xffffull) << 16);
            // LDS-only fence, then relaxed bump (no vmcnt drain)
            asm volatile("s_waitcnt lgkmcnt(0)" ::: "memory");
            __builtin_amdgcn_sched_barrier(0);
            if (l == 0)
                __hip_atomic_store(&rp[0], (unsigned int)(t + 1),
                                   __ATOMIC_RELAXED, __HIP_MEMORY_SCOPE_WORKGROUP);
        }
    } else {
        // ------------- compute waves -------------
        const float* xptr = x + cg * 12;
        float xr[12];
        #pragma unroll
        for (int i = 0; i < 12; ++i) xr[i] = 0.0f;   // x[-1] = 0
        float syn = 0.f, mem = 0.f, prev = 0.f;

        for (int t = 0; t < T_STEPS; ++t) {
            // issue x[t] prefetch (consumed next step); overlaps the spin
            const float4* xp4 = (const float4*)xptr;
            float4 f0 = xp4[0], f1 = xp4[1], f2 = xp4[2];

            // acquire-spin: remote bits (rdySync>=t) and own bits (rdyOwn>=t)
            unsigned long long rv = __hip_atomic_load(&rdyPack, __ATOMIC_ACQUIRE,
                                        __HIP_MEMORY_SCOPE_WORKGROUP);
            while ((unsigned int)rv < (unsigned int)t ||
                   (unsigned int)(rv >> 32) < (unsigned int)t) {
                #pragma unroll
                for (int i = 0; i < 4; ++i) {   // burn under LDS latency
                    u0 = fmaf(u0, bc, bd); u1 = fmaf(u1, bc, bd);
                    u2 = fmaf(u2, bc, bd); u3 = fmaf(u3, bc, bd);
                }
                rv = __hip_atomic_load(&rdyPack, __ATOMIC_ACQUIRE,
                                       __HIP_MEMORY_SCOPE_WORKGROUP);
            }

            const int slot = (t + RING - 1) & (RING - 1);   // (t-1) & 3
            unsigned int b0 = bits_lds[slot][2 * cg];       // cols cg*64..+31
            unsigned int b1 = bits_lds[slot][2 * cg + 1];   // cols +32..+63

            // V @ S_{t-1} over my 64 columns (two parallel FMA chains)
            float a0 = 0.f, a1 = 0.f;
            #pragma unroll
            for (int i = 0; i < 8; ++i) {
                a0 = fmaf((float)((b0 >> (4 * i + 0)) & 1u), vfrag[i].x, a0);
                a0 = fmaf((float)((b0 >> (4 * i + 1)) & 1u), vfrag[i].y, a0);
                a0 = fmaf((float)((b0 >> (4 * i + 2)) & 1u), vfrag[i].z, a0);
                a0 = fmaf((float)((b0 >> (4 * i + 3)) & 1u), vfrag[i].w, a0);
                a1 = fmaf((float)((b1 >> (4 * i + 0)) & 1u), vfrag[8 + i].x, a1);
                a1 = fmaf((float)((b1 >> (4 * i + 1)) & 1u), vfrag[8 + i].y, a1);
                a1 = fmaf((float)((b1 >> (4 * i + 2)) & 1u), vfrag[8 + i].z, a1);
                a1 = fmaf((float)((b1 >> (4 * i + 3)) & 1u), vfrag[8 + i].w, a1);
            }
            // + W_in @ x[t-1] over my 12 k's
            #pragma unroll
            for (int i = 0; i < 12; ++i) a0 = fmaf(wfrag[i], xr[i], a0);
            float acc = a0 + a1;

            // reduce across the row's 16 lanes
            #pragma unroll
            for (int m = 1; m < 16; m <<= 1) acc += __shfl_xor(acc, m, 64);

            // state update (identical across the row's 16 lanes)
            float cur = acc + b_r;
            syn = fmaf(ah, syn, cur);
            mem = fmaf(bh, mem, syn) * (1.0f - prev);   // zero-reset, prev spike
            float spk = (mem > 1.0f) ? 1.0f : 0.0f;
            prev = spk;

            // combine: ballot -> lane0 packs 4-bit nibble -> LDS u64 add
            unsigned long long bal = __ballot(spk > 0.5f);
            unsigned int isLast = 0u, bitsAll = 0u;
            if (l == 0) {
                unsigned int nib = (unsigned int)(bal & 1ull)
                                 | ((unsigned int)((bal >> 16) & 1ull) << 1)
                                 | ((unsigned int)((bal >> 32) & 1ull) << 2)
                                 | ((unsigned int)((bal >> 48) & 1ull) << 3);
                unsigned long long add =
                    (1ull << 32) | ((unsigned long long)nib << (4 * w));
                unsigned long long old = __hip_atomic_fetch_add(&combine[t & 1],
                        add, __ATOMIC_RELAXED, __HIP_MEMORY_SCOPE_WORKGROUP);
                unsigned long long nv = old + add;
                if ((nv >> 32) == 8ull) { isLast = 1u; bitsAll = (unsigned int)nv; }
            }
            isLast = __shfl(isLast, 0, 64);
            if (isLast) {
                unsigned int bits = __shfl(bitsAll, 0, 64);
                unsigned int want = (unsigned int)(t + 1);
                unsigned int w0t = (want << 16) | (bits & 0xffffu);
                unsigned int w1t = (want << 16) | (bits >> 16);
                unsigned long long pack =
                    (unsigned long long)w0t | ((unsigned long long)w1t << 32);
                // fire-and-forget: tagged flags are self-validating, no fence
                if (l < NBLK && l != blk) {
                    __hip_atomic_store(
                        &mbox[(size_t)(((t & (RING - 1)) * NBLK + l) * NBLK) + blk],
                        pack, __ATOMIC_RELAXED, __HIP_MEMORY_SCOPE_AGENT);
                }
                if (l == 0) {
                    bits_lds[t & (RING - 1)][blk] = bits;   // own bits
                    combine[t & 1] = 0ull;                  // re-arm for t+2
                    // LDS-only fence, then relaxed bump (no vmcnt drain)
                    asm volatile("s_waitcnt lgkmcnt(0)" ::: "memory");
                    __builtin_amdgcn_sched_barrier(0);
                    __hip_atomic_store(&rp[1], (unsigned int)(t + 1),
                                       __ATOMIC_RELAXED,
                                       __HIP_MEMORY_SCOPE_WORKGROUP);
                    // raster write AFTER the bump: off the critical path
                    raster[(size_t)t * NBLK + blk] = make_uint2(w0t, w1t);
                }
            }

            #pragma unroll
            for (int i = 0; i < 4; ++i) {
                xr[i]     = (&f0.x)[i];
                xr[4 + i] = (&f1.x)[i];
                xr[8 + i] = (&f2.x)[i];
            }
            xptr += IN_DIM;
        }
    }
    // keep burn chains alive (prevents DCE; negligible cost)
    asm volatile("" :: "v"(u0), "v"(u1), "v"(u2), "v"(u3));
}

// ---------------------------------------------------------------- phase 2A
// R[t][rr] = W_out[rr] . S_{t-1}  (rr = h*2+o, 10 rows). W_out staged in LDS
// with pad (stride 1033) to break row-bank conflicts.
__global__ __launch_bounds__(256, 1) void k_readout_mm(
    const uint2* __restrict__ raster,  // [T][32] tagged words
    const float* __restrict__ W_out,   // [10][1024]
    float* __restrict__ R)             // [T][10]
{
    __shared__ float wlds[10 * 1033];
    for (int i = threadIdx.x; i < 10 * 1024; i += 256) {
        int r = i >> 10, c = i & 1023;
        wlds[r * 1033 + c] = W_out[i];
    }
    __syncthreads();

    int tid = threadIdx.x;
    if (tid >= 250) return;
    int tl = tid / 10, rowr = tid - tl * 10;
    int t = blockIdx.x * 25 + tl;
    if (t >= T_STEPS) return;

    float acc = 0.f;
    if (t > 0) {
        const uint2* wp = raster + (size_t)(t - 1) * NBLK;
        const float* wr = &wlds[rowr * 1033];
        for (int ww = 0; ww < NBLK; ++ww) {
            uint2 v = wp[ww];
            unsigned int bits = (v.x & 0xffffu) | ((v.y & 0xffffu) << 16);
            const float* wb = wr + ww * 32;
            #pragma unroll
            for (int j = 0; j < 32; ++j)
                acc = fmaf((float)((bits >> j) & 1u), wb[j], acc);
        }
    }
    R[t * 10 + rowr] = acc;
}

// ---------------------------------------------------------------- phase 2B
__global__ void k_scan(const float* __restrict__ R,
                       const float* __restrict__ alpha_r,
                       const float* __restrict__ beta_r,
                       float* __restrict__ memr_all)   // [T][10]
{
    int lane = threadIdx.x;
    bool act = lane < 10;
    float a = act ? alpha_r[lane >> 1] : 0.f;
    float b = act ? beta_r[lane >> 1] : 0.f;
    float syn = 0.f, mem = 0.f;
    constexpr int PF = 8;
    float buf[PF];
    #pragma unroll
    for (int i = 0; i < PF; ++i) buf[i] = act ? R[i * 10 + lane] : 0.f;

    for (int tb = 0; tb < T_STEPS; tb += PF) {
        #pragma unroll
        for (int i = 0; i < PF; ++i) {
            int t = tb + i;
            syn = fmaf(a, syn, buf[i]);
            mem = fmaf(b, mem, syn);
            if (act) memr_all[t * 10 + lane] = mem;
            int tn = t + PF;
            buf[i] = (act && tn < T_STEPS) ? R[tn * 10 + lane] : 0.f;
        }
    }
}

// ---------------------------------------------------------------- phase 2C
__global__ void k_mean(const float* __restrict__ memr_all, float* __restrict__ out) {
    int g = blockIdx.x * blockDim.x + threadIdx.x;
    if (g >= T_STEPS * 2) return;
    int t = g >> 1, o = g & 1;
    const float* m = memr_all + t * 10 + o;
    out[g] = 0.2f * (m[0] + m[2] + m[4] + m[6] + m[8]);
}

// ---------------------------------------------------------------- launch
extern "C" void kernel_launch(void* const* d_in, const int* in_sizes, int n_in,
                              void* d_out, int out_size, void* d_ws, size_t ws_size,
                              hipStream_t stream) {
    (void)in_sizes; (void)n_in; (void)out_size; (void)ws_size;
    const float* x       = (const float*)d_in[0];
    const float* W_in    = (const float*)d_in[1];
    const float* V       = (const float*)d_in[2];
    const float* b_rec   = (const float*)d_in[3];
    const float* W_out   = (const float*)d_in[4];
    const float* alpha_h = (const float*)d_in[5];
    const float* beta_h  = (const float*)d_in[6];
    const float* alpha_r = (const float*)d_in[7];
    const float* beta_r  = (const float*)d_in[8];
    float* out = (float*)d_out;

    char* wsb = (char*)d_ws;
    unsigned long long* mbox = (unsigned long long*)wsb;   // 4*32*32*8 = 32 KB
    uint2* raster  = (uint2*)(wsb + RING * NBLK * NBLK * 8);          // 2 MB
    float* Rbuf    = (float*)(wsb + RING * NBLK * NBLK * 8
                              + (size_t)T_STEPS * NBLK * 8);          // 320 KB
    float* memr_all = Rbuf + (size_t)T_STEPS * 10;                    // 320 KB

    int nclr = RING * NBLK * NBLK * 2;   // mailbox region in u32s
    k_clear<<<(nclr + 255) / 256, 256, 0, stream>>>((unsigned int*)mbox, nclr);
    k_phase1<<<NBLK, 576, 0, stream>>>(x, W_in, V, b_rec, alpha_h, beta_h,
                                       mbox, raster);
    k_readout_mm<<<(T_STEPS + 24) / 25, 256, 0, stream>>>(raster, W_out, Rbuf);
    k_scan<<<1, 64, 0, stream>>>(Rbuf, alpha_r, beta_r, memr_all);
    k_mean<<<(T_STEPS * 2 + 255) / 256, 256, 0, stream>>>(memr_all, out);
}